// Round 11
// baseline (432.549 us; speedup 1.0000x reference)
//
#include <hip/hip_runtime.h>
#include <hip/hip_bf16.h>
#include <stdint.h>

#define B_ 2
#define N_ 20000
#define H_ 256
#define E_ 160000
#define M_ 512

typedef short bf16x8 __attribute__((ext_vector_type(8)));
typedef float f32x4 __attribute__((ext_vector_type(4)));
typedef unsigned u32x4 __attribute__((ext_vector_type(4)));

__device__ __forceinline__ unsigned short f2bf(float f) {
    union { float f; unsigned u; } cv; cv.f = f;
    unsigned u = cv.u;
    unsigned r = u + 0x7fffu + ((u >> 16) & 1u);
    return (unsigned short)(r >> 16);
}
__device__ __forceinline__ unsigned pack2(float a, float b) {
    return (unsigned)f2bf(a) | ((unsigned)f2bf(b) << 16);
}
__device__ __forceinline__ float bflo(unsigned p) {
    union { unsigned u; float f; } c; c.u = p << 16; return c.f;
}

// ---------- merged weight transpose/convert ----------
__device__ __forceinline__ void conv_t_one(const float* __restrict__ W,
                                           unsigned short* __restrict__ Wt,
                                           int K, int Ncol, int idx) {
    int n = idx % Ncol;
    int kc = (idx / Ncol) << 3;
    unsigned short t[8];
#pragma unroll
    for (int j = 0; j < 8; ++j) t[j] = f2bf(W[(size_t)(kc + j) * Ncol + n]);
    u32x4 v;
    v.x = (unsigned)t[0] | ((unsigned)t[1] << 16);
    v.y = (unsigned)t[2] | ((unsigned)t[3] << 16);
    v.z = (unsigned)t[4] | ((unsigned)t[5] << 16);
    v.w = (unsigned)t[6] | ((unsigned)t[7] << 16);
    *(u32x4*)(Wt + (size_t)n * K + kc) = v;
}

// W1pq[jj][kk]: jj<512 -> P col: W1[kk][jj]; jj>=512 -> Q col: W1[kk+256][jj-512]
__device__ __forceinline__ void conv_w1pq_one(const float* __restrict__ W,
                                              unsigned short* __restrict__ Wt, int idx) {
    int jj = idx & 1023;
    int kc = (idx >> 10) << 3;
    int koff = (jj >= 512) ? 256 : 0;
    int j = jj & 511;
    unsigned short t[8];
#pragma unroll
    for (int r = 0; r < 8; ++r) t[r] = f2bf(W[(size_t)(kc + r + koff) * 512 + j]);
    u32x4 v;
    v.x = (unsigned)t[0] | ((unsigned)t[1] << 16);
    v.y = (unsigned)t[2] | ((unsigned)t[3] << 16);
    v.z = (unsigned)t[4] | ((unsigned)t[5] << 16);
    v.w = (unsigned)t[6] | ((unsigned)t[7] << 16);
    *(u32x4*)(Wt + (size_t)jj * 256 + kc) = v;
}

__global__ void conv_all(const float* __restrict__ mw1, const float* __restrict__ mw2,
                         const float* __restrict__ uw1, const float* __restrict__ uw2,
                         unsigned short* __restrict__ w1pq, unsigned short* __restrict__ w2t,
                         unsigned short* __restrict__ u1t, unsigned short* __restrict__ u2t) {
    int idx = blockIdx.x * blockDim.x + threadIdx.x;
    if (idx < 32768) {
        conv_w1pq_one(mw1, w1pq, idx);
    } else if (idx < 49152) {
        conv_t_one(mw2, w2t, 512, 256, idx - 32768);
    } else if (idx < 81920) {
        conv_t_one(uw1, u1t, 512, 512, idx - 49152);
    } else if (idx < 98304) {
        conv_t_one(uw2, u2t, 512, 256, idx - 81920);
    }
}

// ---------- edge sort by dst (counting sort; store SRC directly) ----------
__global__ void hist_kernel(const int* __restrict__ eidx, int* __restrict__ cnt) {
    for (int e = blockIdx.x * blockDim.x + threadIdx.x; e < E_;
         e += gridDim.x * blockDim.x)
        atomicAdd(cnt + eidx[E_ + e], 1);
}

__global__ void scan_kernel(const int* __restrict__ cnt, int* __restrict__ offs,
                            int* __restrict__ cursor) {
    __shared__ int part[1024];
    int t = threadIdx.x;
    int base_i = t * 20;
    int loc[20];
    int s = 0;
#pragma unroll 20
    for (int i = 0; i < 20; ++i) {
        int idx = base_i + i;
        int v = (idx < N_) ? cnt[idx] : 0;
        loc[i] = s;
        s += v;
    }
    part[t] = s;
    __syncthreads();
    for (int off = 1; off < 1024; off <<= 1) {
        int tmp = (t >= off) ? part[t - off] : 0;
        __syncthreads();
        if (t >= off) part[t] += tmp;
        __syncthreads();
    }
    int base = part[t] - s;
#pragma unroll 20
    for (int i = 0; i < 20; ++i) {
        int idx = base_i + i;
        if (idx < N_) {
            int o = base + loc[i];
            offs[idx] = o;
            cursor[idx] = o;
        }
    }
    if (t == 1023) offs[N_] = part[1023];
}

__global__ void scatter_kernel(const int* __restrict__ eidx, int* __restrict__ cursor,
                               int* __restrict__ srcs) {
    for (int e = blockIdx.x * blockDim.x + threadIdx.x; e < E_;
         e += gridDim.x * blockDim.x) {
        int d = eidx[E_ + e];
        int pos = atomicAdd(cursor + d, 1);
        srcs[pos] = eidx[e];
    }
}

// ---------- PQ = h @ [W1a | W1b]  (nrows, K=256, 1024 cols) ----------
__global__ __launch_bounds__(512, 4) void pq_gemm(
    const float* __restrict__ hb,
    const unsigned short* __restrict__ W1pq,  // [1024][256] bf16
    unsigned short* __restrict__ PQ,          // [nrows][1024] bf16
    int nrows) {
    __shared__ char smem[64 * 512];  // 32 KB
    const int tid = threadIdx.x;
    const int tile = blockIdx.x >> 1;
    const int qh = blockIdx.x & 1;
    const int row0 = tile * 64;

#pragma unroll
    for (int it = 0; it < 8; ++it) {
        int linear = it * 512 + tid;
        int row = linear >> 6;
        int c4 = linear & 63;
        int grow = row0 + row;
        if (grow >= nrows) grow = nrows - 1;
        f32x4 v = *(const f32x4*)(hb + (size_t)grow * H_ + c4 * 4);
        int byte = (row * 512 + c4 * 8) ^ ((row & 7) << 4);
        uint2 p;
        p.x = pack2(v.x, v.y);
        p.y = pack2(v.z, v.w);
        *(uint2*)(smem + byte) = p;
    }
    __syncthreads();

    const int lane = tid & 63;
    const int w = tid >> 6;
    const int lo = lane & 15;
    const int hi = lane >> 4;
    const int colw = qh * 512 + w * 64;

    f32x4 acc[4][4];
#pragma unroll
    for (int i = 0; i < 4; ++i)
#pragma unroll
        for (int j = 0; j < 4; ++j) acc[i][j] = (f32x4){0.f, 0.f, 0.f, 0.f};

#pragma unroll
    for (int ks = 0; ks < 256; ks += 32) {
        bf16x8 af[4];
#pragma unroll
        for (int rf = 0; rf < 4; ++rf) {
            int row = rf * 16 + lo;
            int byte = (row * 512 + (ks + 8 * hi) * 2) ^ ((row & 7) << 4);
            af[rf] = *(const bf16x8*)(smem + byte);
        }
#pragma unroll
        for (int cf = 0; cf < 4; ++cf) {
            bf16x8 bfr = *(const bf16x8*)(W1pq + (size_t)(colw + cf * 16 + lo) * 256 + ks + 8 * hi);
#pragma unroll
            for (int rf = 0; rf < 4; ++rf)
                acc[rf][cf] = __builtin_amdgcn_mfma_f32_16x16x32_bf16(af[rf], bfr, acc[rf][cf], 0, 0, 0);
        }
    }

#pragma unroll
    for (int cf = 0; cf < 4; ++cf) {
        int col = colw + cf * 16 + lo;
#pragma unroll
        for (int rf = 0; rf < 4; ++rf) {
#pragma unroll
            for (int r = 0; r < 4; ++r) {
                int row = rf * 16 + hi * 4 + r;
                if (row0 + row < nrows)
                    PQ[(size_t)(row0 + row) * 1024 + col] = f2bf(acc[rf][cf][r]);
            }
        }
    }
}

// ---------- edge gather: one wave per dst-row; hiddensum -> global (bf16) ----------
__global__ __launch_bounds__(256, 8) void gather_kernel(
    const unsigned short* __restrict__ PQ,
    const int* __restrict__ srcs,
    const int* __restrict__ offs,
    const float* __restrict__ mb1,
    unsigned short* __restrict__ hsum,        // [ndst][512] bf16
    int ndst) {
    const int lane = threadIdx.x & 63;
    const int nw = (gridDim.x * blockDim.x) >> 6;
    const int wid0 = (blockIdx.x * blockDim.x + threadIdx.x) >> 6;

    float bq[8];
#pragma unroll
    for (int j = 0; j < 8; ++j) bq[j] = mb1[lane * 8 + j];

    for (int dd = wid0; dd < ndst; dd += nw) {
        int d = dd;
        size_t bofs = 0;
        if (dd >= N_) { d = dd - N_; bofs = (size_t)N_ * 1024; }
        const unsigned short* PQb = PQ + bofs;

        bf16x8 qv = *(const bf16x8*)(PQ + (size_t)dd * 1024 + 512 + lane * 8);
        float qb[8];
#pragma unroll
        for (int j = 0; j < 8; ++j)
            qb[j] = bflo((unsigned)(unsigned short)qv[j]) + bq[j];

        float acc[8];
#pragma unroll
        for (int j = 0; j < 8; ++j) acc[j] = 0.f;

        int p = offs[d];
        const int end = offs[d + 1];
        for (; p + 3 < end; p += 4) {
            int s0 = srcs[p];
            int s1 = srcs[p + 1];
            int s2 = srcs[p + 2];
            int s3 = srcs[p + 3];
            bf16x8 v0 = *(const bf16x8*)(PQb + (size_t)s0 * 1024 + lane * 8);
            bf16x8 v1 = *(const bf16x8*)(PQb + (size_t)s1 * 1024 + lane * 8);
            bf16x8 v2 = *(const bf16x8*)(PQb + (size_t)s2 * 1024 + lane * 8);
            bf16x8 v3 = *(const bf16x8*)(PQb + (size_t)s3 * 1024 + lane * 8);
#pragma unroll
            for (int j = 0; j < 8; ++j) {
                float q = qb[j];
                acc[j] += fmaxf(bflo((unsigned)(unsigned short)v0[j]) + q, 0.f)
                        + fmaxf(bflo((unsigned)(unsigned short)v1[j]) + q, 0.f)
                        + fmaxf(bflo((unsigned)(unsigned short)v2[j]) + q, 0.f)
                        + fmaxf(bflo((unsigned)(unsigned short)v3[j]) + q, 0.f);
            }
        }
        for (; p < end; ++p) {
            int s0 = srcs[p];
            bf16x8 v0 = *(const bf16x8*)(PQb + (size_t)s0 * 1024 + lane * 8);
#pragma unroll
            for (int j = 0; j < 8; ++j)
                acc[j] += fmaxf(bflo((unsigned)(unsigned short)v0[j]) + qb[j], 0.f);
        }

        u32x4 v;
        v.x = pack2(acc[0], acc[1]);
        v.y = pack2(acc[2], acc[3]);
        v.z = pack2(acc[4], acc[5]);
        v.w = pack2(acc[6], acc[7]);
        *(u32x4*)(hsum + (size_t)dd * 512 + lane * 8) = v;
    }
}

// ---------- fused msg-GEMM2 + update MLP (32 rows/block, 4 blocks/CU) ----------
// LDS 32.5 KB; accumulators <= 32 VGPR -> high occupancy. Streaming traffic nontemporal.
__global__ __launch_bounds__(512, 8) void mlp_kernel(
    const unsigned short* __restrict__ hsum,  // [nrows][512] bf16
    const int* __restrict__ cnt,
    const unsigned short* __restrict__ w2t,   // [256][512]
    const float* __restrict__ mb2,
    const unsigned short* __restrict__ u1t,   // [512][512]
    const float* __restrict__ ub1,
    const unsigned short* __restrict__ u2t,   // [256][512]
    const float* __restrict__ ub2,
    const float* __restrict__ hb,
    float* __restrict__ outb,
    int nrows) {
    __shared__ char smA[32 * 1024];
    __shared__ int s_cnt[32];

    const int tid = threadIdx.x;
    const int d0 = blockIdx.x * 32;

    if (tid < 32) {
        int dd = d0 + tid;
        if (dd >= nrows) dd = nrows - 1;
        int node = (dd >= N_) ? dd - N_ : dd;
        s_cnt[tid] = cnt[node];
    }

    // ---- 1. stage hiddensum -> smA: 32 rows x 64 16B-chunks (2048 chunks, 4 iters) ----
#pragma unroll
    for (int it = 0; it < 4; ++it) {
        int linear = it * 512 + tid;
        int row = linear >> 6;
        int c8 = linear & 63;
        int dd = d0 + row;
        if (dd >= nrows) dd = nrows - 1;
        u32x4 v = __builtin_nontemporal_load((const u32x4*)(hsum + (size_t)dd * 512 + c8 * 8));
        int byte = (row * 1024 + c8 * 16) ^ ((row & 7) << 4);
        *(u32x4*)(smA + byte) = v;
    }
    __syncthreads();

    const int lane = tid & 63;
    const int w = tid >> 6;
    const int lo = lane & 15;
    const int hi = lane >> 4;

    // ---- 2. phase B: agg = hiddensum @ W2 (regs); wave w cols [32w, 32w+32) ----
    f32x4 aB[2][2];
#pragma unroll
    for (int i = 0; i < 2; ++i)
#pragma unroll
        for (int j = 0; j < 2; ++j) aB[i][j] = (f32x4){0.f, 0.f, 0.f, 0.f};
    {
        const int colw = w * 32;
        for (int ks = 0; ks < 512; ks += 32) {
            bf16x8 af[2];
#pragma unroll
            for (int rf = 0; rf < 2; ++rf) {
                int row = rf * 16 + lo;
                int byte = (row * 1024 + (ks + 8 * hi) * 2) ^ ((row & 7) << 4);
                af[rf] = *(const bf16x8*)(smA + byte);
            }
#pragma unroll
            for (int cf = 0; cf < 2; ++cf) {
                bf16x8 bfr = *(const bf16x8*)(w2t + (size_t)(colw + cf * 16 + lo) * 512 + ks + 8 * hi);
#pragma unroll
                for (int rf = 0; rf < 2; ++rf)
                    aB[rf][cf] = __builtin_amdgcn_mfma_f32_16x16x32_bf16(af[rf], bfr, aB[rf][cf], 0, 0, 0);
            }
        }
    }
    __syncthreads();  // hiddensum reads done

    // ---- 3. restage smA = X = [h(bf16) | agg] ----
#pragma unroll
    for (int it = 0; it < 2; ++it) {
        int linear = it * 512 + tid;   // 1024 chunks: 32 rows x 32 chunks
        int row = linear >> 5;
        int c8 = linear & 31;
        int grow = d0 + row;
        if (grow >= nrows) grow = nrows - 1;
        const float* src = hb + (size_t)grow * H_ + c8 * 8;
        f32x4 a = __builtin_nontemporal_load((const f32x4*)src);
        f32x4 b = __builtin_nontemporal_load((const f32x4*)(src + 4));
        u32x4 v;
        v.x = pack2(a.x, a.y);
        v.y = pack2(a.z, a.w);
        v.z = pack2(b.x, b.y);
        v.w = pack2(b.z, b.w);
        int byte = (row * 1024 + c8 * 16) ^ ((row & 7) << 4);
        *(u32x4*)(smA + byte) = v;
    }
    {
        const int colw = w * 32;
#pragma unroll
        for (int cf = 0; cf < 2; ++cf) {
            int col = colw + cf * 16 + lo;
            float bb = mb2[col];
#pragma unroll
            for (int rf = 0; rf < 2; ++rf) {
#pragma unroll
                for (int r = 0; r < 4; ++r) {
                    int row = rf * 16 + hi * 4 + r;
                    float v = aB[rf][cf][r] + (float)s_cnt[row] * bb;
                    int byte = (row * 1024 + (256 + col) * 2) ^ ((row & 7) << 4);
                    *(unsigned short*)(smA + byte) = f2bf(v);
                }
            }
        }
    }
    __syncthreads();

    // ---- 4. phase C: hid2 = relu(X @ U1 + ub1) (regs); wave w cols [64w, 64w+64) ----
    f32x4 aC[2][4];
#pragma unroll
    for (int i = 0; i < 2; ++i)
#pragma unroll
        for (int j = 0; j < 4; ++j) aC[i][j] = (f32x4){0.f, 0.f, 0.f, 0.f};
    {
        const int colw = w * 64;
        for (int ks = 0; ks < 512; ks += 32) {
            bf16x8 af[2];
#pragma unroll
            for (int rf = 0; rf < 2; ++rf) {
                int row = rf * 16 + lo;
                int byte = (row * 1024 + (ks + 8 * hi) * 2) ^ ((row & 7) << 4);
                af[rf] = *(const bf16x8*)(smA + byte);
            }
#pragma unroll
            for (int cf = 0; cf < 4; ++cf) {
                bf16x8 bfr = *(const bf16x8*)(u1t + (size_t)(colw + cf * 16 + lo) * 512 + ks + 8 * hi);
#pragma unroll
                for (int rf = 0; rf < 2; ++rf)
                    aC[rf][cf] = __builtin_amdgcn_mfma_f32_16x16x32_bf16(af[rf], bfr, aC[rf][cf], 0, 0, 0);
            }
        }
    }
    __syncthreads();  // X reads done

    // ---- 5. write hid2 -> smA ----
    {
        const int colw = w * 64;
#pragma unroll
        for (int cf = 0; cf < 4; ++cf) {
            int col = colw + cf * 16 + lo;
            float bb = ub1[col];
#pragma unroll
            for (int rf = 0; rf < 2; ++rf) {
#pragma unroll
                for (int r = 0; r < 4; ++r) {
                    float v = fmaxf(aC[rf][cf][r] + bb, 0.f);
                    int row = rf * 16 + hi * 4 + r;
                    int byte = (row * 1024 + col * 2) ^ ((row & 7) << 4);
                    *(unsigned short*)(smA + byte) = f2bf(v);
                }
            }
        }
    }
    __syncthreads();

    // ---- 6. phase D: out = h + hid2 @ U2 + ub2; wave w cols [32w, 32w+32) ----
    {
        const int colw = w * 32;
        f32x4 aD[2][2];
#pragma unroll
        for (int i = 0; i < 2; ++i)
#pragma unroll
            for (int j = 0; j < 2; ++j) aD[i][j] = (f32x4){0.f, 0.f, 0.f, 0.f};

        for (int ks = 0; ks < 512; ks += 32) {
            bf16x8 af[2];
#pragma unroll
            for (int rf = 0; rf < 2; ++rf) {
                int row = rf * 16 + lo;
                int byte = (row * 1024 + (ks + 8 * hi) * 2) ^ ((row & 7) << 4);
                af[rf] = *(const bf16x8*)(smA + byte);
            }
#pragma unroll
            for (int cf = 0; cf < 2; ++cf) {
                bf16x8 bfr = *(const bf16x8*)(u2t + (size_t)(colw + cf * 16 + lo) * 512 + ks + 8 * hi);
#pragma unroll
                for (int rf = 0; rf < 2; ++rf)
                    aD[rf][cf] = __builtin_amdgcn_mfma_f32_16x16x32_bf16(af[rf], bfr, aD[rf][cf], 0, 0, 0);
            }
        }

#pragma unroll
        for (int cf = 0; cf < 2; ++cf) {
            int col = colw + cf * 16 + lo;
            float bb = ub2[col];
#pragma unroll
            for (int rf = 0; rf < 2; ++rf) {
#pragma unroll
                for (int r = 0; r < 4; ++r) {
                    int row = rf * 16 + hi * 4 + r;
                    int grow = d0 + row;
                    if (grow < nrows) {
                        size_t o = (size_t)grow * H_ + col;
                        float hv = hb[o];
                        __builtin_nontemporal_store(hv + aD[rf][cf][r] + bb, &outb[o]);
                    }
                }
            }
        }
    }
}

extern "C" void kernel_launch(void* const* d_in, const int* in_sizes, int n_in,
                              void* d_out, int out_size, void* d_ws, size_t ws_size,
                              hipStream_t stream) {
    const float* h      = (const float*)d_in[0];
    const int*   eidx   = (const int*)d_in[1];
    const float* msg_w1 = (const float*)d_in[2];
    const float* msg_b1 = (const float*)d_in[3];
    const float* msg_w2 = (const float*)d_in[4];
    const float* msg_b2 = (const float*)d_in[5];
    const float* upd_w1 = (const float*)d_in[6];
    const float* upd_b1 = (const float*)d_in[7];
    const float* upd_w2 = (const float*)d_in[8];
    const float* upd_b2 = (const float*)d_in[9];
    float* out = (float*)d_out;

    // ---- workspace layout: try batch-merged, fall back to per-batch ----
    const size_t smallSizes[] = {
        (size_t)2 * N_ * 1024 * 2,   // PQ      (merged: [2N][1024])
        (size_t)2 * N_ * 512 * 2,    // hsum    (merged: [2N][512])
        1024 * 256 * 2,              // w1pq
        256 * 512 * 2,               // w2t
        512 * 512 * 2,               // u1t
        256 * 512 * 2,               // u2t
        (size_t)N_ * 4,              // cnt
        (size_t)(N_ + 1) * 4,        // offs
        (size_t)N_ * 4,              // cursor
        (size_t)E_ * 4               // srcs
    };
    size_t needMerged = 0;
    for (int i = 0; i < 10; ++i) needMerged += (smallSizes[i] + 255) & ~(size_t)255;
    const bool merged = (ws_size >= needMerged);

    char* ws = (char*)d_ws;
    size_t off = 0;
    auto alloc = [&](size_t bytes) {
        char* p = ws + off;
        off = (off + bytes + 255) & ~(size_t)255;
        return p;
    };
    const int PQ_ROWS = merged ? 2 * N_ : N_;
    unsigned short* PQ   = (unsigned short*)alloc((size_t)PQ_ROWS * 1024 * 2);
    unsigned short* hsum = (unsigned short*)alloc((size_t)PQ_ROWS * 512 * 2);
    unsigned short* w1pq = (unsigned short*)alloc(1024 * 256 * 2);
    unsigned short* w2t  = (unsigned short*)alloc(256 * 512 * 2);
    unsigned short* u1t  = (unsigned short*)alloc(512 * 512 * 2);
    unsigned short* u2t  = (unsigned short*)alloc(256 * 512 * 2);
    int* cnt    = (int*)alloc(N_ * 4);
    int* offs   = (int*)alloc((N_ + 1) * 4);
    int* cursor = (int*)alloc(N_ * 4);
    int* srcs   = (int*)alloc(E_ * 4);
    if (ws_size < off) return;

    hipMemsetAsync(cnt, 0, N_ * 4, stream);
    conv_all<<<384, 256, 0, stream>>>(msg_w1, msg_w2, upd_w1, upd_w2, w1pq, w2t, u1t, u2t);

    hist_kernel<<<256, 256, 0, stream>>>(eidx, cnt);
    scan_kernel<<<1, 1024, 0, stream>>>(cnt, offs, cursor);
    scatter_kernel<<<256, 256, 0, stream>>>(eidx, cursor, srcs);

    if (merged) {
        const int nrows = 2 * N_;                    // 40000
        const int nblk64 = (nrows + 63) / 64;        // 625
        const int nblk32 = (nrows + 31) / 32;        // 1250
        pq_gemm<<<nblk64 * 2, 512, 0, stream>>>(h, w1pq, PQ, nrows);
        gather_kernel<<<2048, 256, 0, stream>>>(PQ, srcs, offs, msg_b1, hsum, nrows);
        mlp_kernel<<<nblk32, 512, 0, stream>>>(hsum, cnt, w2t, msg_b2,
                                               u1t, upd_b1, u2t, upd_b2,
                                               h, out, nrows);
    } else {
        const int nblk64 = (N_ + 63) / 64;           // 313
        const int nblk32 = (N_ + 31) / 32;           // 625
        for (int b = 0; b < B_; ++b) {
            const float* hb = h + (size_t)b * N_ * H_;
            pq_gemm<<<nblk64 * 2, 512, 0, stream>>>(hb, w1pq, PQ, N_);
            gather_kernel<<<2048, 256, 0, stream>>>(PQ, srcs, offs, msg_b1, hsum, N_);
            mlp_kernel<<<nblk32, 512, 0, stream>>>(hsum, cnt, w2t, msg_b2,
                                                   u1t, upd_b1, u2t, upd_b2,
                                                   hb, out + (size_t)b * N_ * H_, N_);
        }
    }
}

// Round 12
// 410.959 us; speedup vs baseline: 1.0525x; 1.0525x over previous
//
#include <hip/hip_runtime.h>
#include <hip/hip_bf16.h>
#include <stdint.h>

#define B_ 2
#define N_ 20000
#define H_ 256
#define E_ 160000
#define M_ 512

typedef short bf16x8 __attribute__((ext_vector_type(8)));
typedef float f32x4 __attribute__((ext_vector_type(4)));
typedef unsigned u32x4 __attribute__((ext_vector_type(4)));

__device__ __forceinline__ unsigned short f2bf(float f) {
    union { float f; unsigned u; } cv; cv.f = f;
    unsigned u = cv.u;
    unsigned r = u + 0x7fffu + ((u >> 16) & 1u);
    return (unsigned short)(r >> 16);
}
__device__ __forceinline__ unsigned pack2(float a, float b) {
    return (unsigned)f2bf(a) | ((unsigned)f2bf(b) << 16);
}
__device__ __forceinline__ float bflo(unsigned p) {
    union { unsigned u; float f; } c; c.u = p << 16; return c.f;
}

// ---------- merged weight transpose/convert ----------
__device__ __forceinline__ void conv_t_one(const float* __restrict__ W,
                                           unsigned short* __restrict__ Wt,
                                           int K, int Ncol, int idx) {
    int n = idx % Ncol;
    int kc = (idx / Ncol) << 3;
    unsigned short t[8];
#pragma unroll
    for (int j = 0; j < 8; ++j) t[j] = f2bf(W[(size_t)(kc + j) * Ncol + n]);
    u32x4 v;
    v.x = (unsigned)t[0] | ((unsigned)t[1] << 16);
    v.y = (unsigned)t[2] | ((unsigned)t[3] << 16);
    v.z = (unsigned)t[4] | ((unsigned)t[5] << 16);
    v.w = (unsigned)t[6] | ((unsigned)t[7] << 16);
    *(u32x4*)(Wt + (size_t)n * K + kc) = v;
}

// W1pq[jj][kk]: jj<512 -> P col: W1[kk][jj]; jj>=512 -> Q col: W1[kk+256][jj-512]
__device__ __forceinline__ void conv_w1pq_one(const float* __restrict__ W,
                                              unsigned short* __restrict__ Wt, int idx) {
    int jj = idx & 1023;
    int kc = (idx >> 10) << 3;
    int koff = (jj >= 512) ? 256 : 0;
    int j = jj & 511;
    unsigned short t[8];
#pragma unroll
    for (int r = 0; r < 8; ++r) t[r] = f2bf(W[(size_t)(kc + r + koff) * 512 + j]);
    u32x4 v;
    v.x = (unsigned)t[0] | ((unsigned)t[1] << 16);
    v.y = (unsigned)t[2] | ((unsigned)t[3] << 16);
    v.z = (unsigned)t[4] | ((unsigned)t[5] << 16);
    v.w = (unsigned)t[6] | ((unsigned)t[7] << 16);
    *(u32x4*)(Wt + (size_t)jj * 256 + kc) = v;
}

__global__ void conv_all(const float* __restrict__ mw1, const float* __restrict__ mw2,
                         const float* __restrict__ uw1, const float* __restrict__ uw2,
                         unsigned short* __restrict__ w1pq, unsigned short* __restrict__ w2t,
                         unsigned short* __restrict__ u1t, unsigned short* __restrict__ u2t) {
    int idx = blockIdx.x * blockDim.x + threadIdx.x;
    if (idx < 32768) {
        conv_w1pq_one(mw1, w1pq, idx);
    } else if (idx < 49152) {
        conv_t_one(mw2, w2t, 512, 256, idx - 32768);
    } else if (idx < 81920) {
        conv_t_one(uw1, u1t, 512, 512, idx - 49152);
    } else if (idx < 98304) {
        conv_t_one(uw2, u2t, 512, 256, idx - 81920);
    }
}

// ---------- edge sort by dst (counting sort; store SRC directly) ----------
__global__ void hist_kernel(const int* __restrict__ eidx, int* __restrict__ cnt) {
    for (int e = blockIdx.x * blockDim.x + threadIdx.x; e < E_;
         e += gridDim.x * blockDim.x)
        atomicAdd(cnt + eidx[E_ + e], 1);
}

__global__ void scan_kernel(const int* __restrict__ cnt, int* __restrict__ offs,
                            int* __restrict__ cursor) {
    __shared__ int part[1024];
    int t = threadIdx.x;
    int base_i = t * 20;
    int loc[20];
    int s = 0;
#pragma unroll 20
    for (int i = 0; i < 20; ++i) {
        int idx = base_i + i;
        int v = (idx < N_) ? cnt[idx] : 0;
        loc[i] = s;
        s += v;
    }
    part[t] = s;
    __syncthreads();
    for (int off = 1; off < 1024; off <<= 1) {
        int tmp = (t >= off) ? part[t - off] : 0;
        __syncthreads();
        if (t >= off) part[t] += tmp;
        __syncthreads();
    }
    int base = part[t] - s;
#pragma unroll 20
    for (int i = 0; i < 20; ++i) {
        int idx = base_i + i;
        if (idx < N_) {
            int o = base + loc[i];
            offs[idx] = o;
            cursor[idx] = o;
        }
    }
    if (t == 1023) offs[N_] = part[1023];
}

__global__ void scatter_kernel(const int* __restrict__ eidx, int* __restrict__ cursor,
                               int* __restrict__ srcs) {
    for (int e = blockIdx.x * blockDim.x + threadIdx.x; e < E_;
         e += gridDim.x * blockDim.x) {
        int d = eidx[E_ + e];
        int pos = atomicAdd(cursor + d, 1);
        srcs[pos] = eidx[e];
    }
}

// ---------- PQ = h @ [W1a | W1b]  (nrows, K=256, 1024 cols) ----------
__global__ __launch_bounds__(512, 4) void pq_gemm(
    const float* __restrict__ hb,
    const unsigned short* __restrict__ W1pq,  // [1024][256] bf16
    unsigned short* __restrict__ PQ,          // [nrows][1024] bf16
    int nrows) {
    __shared__ char smem[64 * 512];  // 32 KB
    const int tid = threadIdx.x;
    const int tile = blockIdx.x >> 1;
    const int qh = blockIdx.x & 1;
    const int row0 = tile * 64;

#pragma unroll
    for (int it = 0; it < 8; ++it) {
        int linear = it * 512 + tid;
        int row = linear >> 6;
        int c4 = linear & 63;
        int grow = row0 + row;
        if (grow >= nrows) grow = nrows - 1;
        f32x4 v = *(const f32x4*)(hb + (size_t)grow * H_ + c4 * 4);
        int byte = (row * 512 + c4 * 8) ^ ((row & 7) << 4);
        uint2 p;
        p.x = pack2(v.x, v.y);
        p.y = pack2(v.z, v.w);
        *(uint2*)(smem + byte) = p;
    }
    __syncthreads();

    const int lane = tid & 63;
    const int w = tid >> 6;
    const int lo = lane & 15;
    const int hi = lane >> 4;
    const int colw = qh * 512 + w * 64;

    f32x4 acc[4][4];
#pragma unroll
    for (int i = 0; i < 4; ++i)
#pragma unroll
        for (int j = 0; j < 4; ++j) acc[i][j] = (f32x4){0.f, 0.f, 0.f, 0.f};

#pragma unroll
    for (int ks = 0; ks < 256; ks += 32) {
        bf16x8 af[4];
#pragma unroll
        for (int rf = 0; rf < 4; ++rf) {
            int row = rf * 16 + lo;
            int byte = (row * 512 + (ks + 8 * hi) * 2) ^ ((row & 7) << 4);
            af[rf] = *(const bf16x8*)(smem + byte);
        }
#pragma unroll
        for (int cf = 0; cf < 4; ++cf) {
            bf16x8 bfr = *(const bf16x8*)(W1pq + (size_t)(colw + cf * 16 + lo) * 256 + ks + 8 * hi);
#pragma unroll
            for (int rf = 0; rf < 4; ++rf)
                acc[rf][cf] = __builtin_amdgcn_mfma_f32_16x16x32_bf16(af[rf], bfr, acc[rf][cf], 0, 0, 0);
        }
    }

#pragma unroll
    for (int cf = 0; cf < 4; ++cf) {
        int col = colw + cf * 16 + lo;
#pragma unroll
        for (int rf = 0; rf < 4; ++rf) {
#pragma unroll
            for (int r = 0; r < 4; ++r) {
                int row = rf * 16 + hi * 4 + r;
                if (row0 + row < nrows)
                    PQ[(size_t)(row0 + row) * 1024 + col] = f2bf(acc[rf][cf][r]);
            }
        }
    }
}

// ---------- edge gather: one wave per dst-row; hiddensum -> global (bf16) ----------
__global__ __launch_bounds__(256, 8) void gather_kernel(
    const unsigned short* __restrict__ PQ,
    const int* __restrict__ srcs,
    const int* __restrict__ offs,
    const float* __restrict__ mb1,
    unsigned short* __restrict__ hsum,        // [ndst][512] bf16
    int ndst) {
    const int lane = threadIdx.x & 63;
    const int nw = (gridDim.x * blockDim.x) >> 6;
    const int wid0 = (blockIdx.x * blockDim.x + threadIdx.x) >> 6;

    float bq[8];
#pragma unroll
    for (int j = 0; j < 8; ++j) bq[j] = mb1[lane * 8 + j];

    for (int dd = wid0; dd < ndst; dd += nw) {
        int d = dd;
        size_t bofs = 0;
        if (dd >= N_) { d = dd - N_; bofs = (size_t)N_ * 1024; }
        const unsigned short* PQb = PQ + bofs;

        bf16x8 qv = *(const bf16x8*)(PQ + (size_t)dd * 1024 + 512 + lane * 8);
        float qb[8];
#pragma unroll
        for (int j = 0; j < 8; ++j)
            qb[j] = bflo((unsigned)(unsigned short)qv[j]) + bq[j];

        float acc[8];
#pragma unroll
        for (int j = 0; j < 8; ++j) acc[j] = 0.f;

        int p = offs[d];
        const int end = offs[d + 1];
        for (; p + 3 < end; p += 4) {
            int s0 = srcs[p];
            int s1 = srcs[p + 1];
            int s2 = srcs[p + 2];
            int s3 = srcs[p + 3];
            bf16x8 v0 = *(const bf16x8*)(PQb + (size_t)s0 * 1024 + lane * 8);
            bf16x8 v1 = *(const bf16x8*)(PQb + (size_t)s1 * 1024 + lane * 8);
            bf16x8 v2 = *(const bf16x8*)(PQb + (size_t)s2 * 1024 + lane * 8);
            bf16x8 v3 = *(const bf16x8*)(PQb + (size_t)s3 * 1024 + lane * 8);
#pragma unroll
            for (int j = 0; j < 8; ++j) {
                float q = qb[j];
                acc[j] += fmaxf(bflo((unsigned)(unsigned short)v0[j]) + q, 0.f)
                        + fmaxf(bflo((unsigned)(unsigned short)v1[j]) + q, 0.f)
                        + fmaxf(bflo((unsigned)(unsigned short)v2[j]) + q, 0.f)
                        + fmaxf(bflo((unsigned)(unsigned short)v3[j]) + q, 0.f);
            }
        }
        for (; p < end; ++p) {
            int s0 = srcs[p];
            bf16x8 v0 = *(const bf16x8*)(PQb + (size_t)s0 * 1024 + lane * 8);
#pragma unroll
            for (int j = 0; j < 8; ++j)
                acc[j] += fmaxf(bflo((unsigned)(unsigned short)v0[j]) + qb[j], 0.f);
        }

        u32x4 v;
        v.x = pack2(acc[0], acc[1]);
        v.y = pack2(acc[2], acc[3]);
        v.z = pack2(acc[4], acc[5]);
        v.w = pack2(acc[6], acc[7]);
        *(u32x4*)(hsum + (size_t)dd * 512 + lane * 8) = v;
    }
}

// ---------- fused msg-GEMM2 + update MLP (64 rows/block) ----------
// K-loops fully unrolled so weight loads pipeline under MFMAs.
__global__ __launch_bounds__(512, 4) void mlp_kernel(
    const unsigned short* __restrict__ hsum,  // [nrows][512] bf16
    const int* __restrict__ cnt,
    const unsigned short* __restrict__ w2t,   // [256][512]
    const float* __restrict__ mb2,
    const unsigned short* __restrict__ u1t,   // [512][512]
    const float* __restrict__ ub1,
    const unsigned short* __restrict__ u2t,   // [256][512]
    const float* __restrict__ ub2,
    const float* __restrict__ hb,
    float* __restrict__ outb,
    int nrows) {
    __shared__ char smA[64 * 1024];
    __shared__ int s_cnt[64];

    const int tid = threadIdx.x;
    const int d0 = blockIdx.x * 64;

    if (tid < 64) {
        int dd = d0 + tid;
        if (dd >= nrows) dd = nrows - 1;
        int node = (dd >= N_) ? dd - N_ : dd;
        s_cnt[tid] = cnt[node];
    }

    // ---- 1. stage hiddensum -> smA: 64 rows x 64 16B-chunks ----
#pragma unroll
    for (int it = 0; it < 8; ++it) {
        int linear = it * 512 + tid;
        int row = linear >> 6;
        int c8 = linear & 63;
        int dd = d0 + row;
        if (dd >= nrows) dd = nrows - 1;
        u32x4 v = *(const u32x4*)(hsum + (size_t)dd * 512 + c8 * 8);
        int byte = (row * 1024 + c8 * 16) ^ ((row & 7) << 4);
        *(u32x4*)(smA + byte) = v;
    }
    __syncthreads();

    const int lane = tid & 63;
    const int w = tid >> 6;
    const int lo = lane & 15;
    const int hi = lane >> 4;

    // ---- 2. phase B: agg = hiddensum @ W2 (regs); wave w cols [32w, 32w+32) ----
    f32x4 aB[4][2];
#pragma unroll
    for (int i = 0; i < 4; ++i)
#pragma unroll
        for (int j = 0; j < 2; ++j) aB[i][j] = (f32x4){0.f, 0.f, 0.f, 0.f};
    {
        const int colw = w * 32;
#pragma unroll
        for (int ks = 0; ks < 512; ks += 32) {
            bf16x8 af[4];
#pragma unroll
            for (int rf = 0; rf < 4; ++rf) {
                int row = rf * 16 + lo;
                int byte = (row * 1024 + (ks + 8 * hi) * 2) ^ ((row & 7) << 4);
                af[rf] = *(const bf16x8*)(smA + byte);
            }
#pragma unroll
            for (int cf = 0; cf < 2; ++cf) {
                bf16x8 bfr = *(const bf16x8*)(w2t + (size_t)(colw + cf * 16 + lo) * 512 + ks + 8 * hi);
#pragma unroll
                for (int rf = 0; rf < 4; ++rf)
                    aB[rf][cf] = __builtin_amdgcn_mfma_f32_16x16x32_bf16(af[rf], bfr, aB[rf][cf], 0, 0, 0);
            }
        }
    }
    __syncthreads();  // hiddensum reads done

    // ---- 3. restage smA = X = [h(bf16) | agg] ----
#pragma unroll
    for (int it = 0; it < 4; ++it) {
        int linear = it * 512 + tid;   // 2048 chunks: 64 rows x 32 chunks
        int row = linear >> 5;
        int c8 = linear & 31;
        int grow = d0 + row;
        if (grow >= nrows) grow = nrows - 1;
        const float* src = hb + (size_t)grow * H_ + c8 * 8;
        f32x4 a = *(const f32x4*)src;
        f32x4 b = *(const f32x4*)(src + 4);
        u32x4 v;
        v.x = pack2(a.x, a.y);
        v.y = pack2(a.z, a.w);
        v.z = pack2(b.x, b.y);
        v.w = pack2(b.z, b.w);
        int byte = (row * 1024 + c8 * 16) ^ ((row & 7) << 4);
        *(u32x4*)(smA + byte) = v;
    }
    {
        const int colw = w * 32;
#pragma unroll
        for (int cf = 0; cf < 2; ++cf) {
            int col = colw + cf * 16 + lo;
            float bb = mb2[col];
#pragma unroll
            for (int rf = 0; rf < 4; ++rf) {
#pragma unroll
                for (int r = 0; r < 4; ++r) {
                    int row = rf * 16 + hi * 4 + r;
                    float v = aB[rf][cf][r] + (float)s_cnt[row] * bb;
                    int byte = (row * 1024 + (256 + col) * 2) ^ ((row & 7) << 4);
                    *(unsigned short*)(smA + byte) = f2bf(v);
                }
            }
        }
    }
    __syncthreads();

    // ---- 4. phase C: hid2 = relu(X @ U1 + ub1) (regs); wave w cols [64w, 64w+64) ----
    f32x4 aC[4][4];
#pragma unroll
    for (int i = 0; i < 4; ++i)
#pragma unroll
        for (int j = 0; j < 4; ++j) aC[i][j] = (f32x4){0.f, 0.f, 0.f, 0.f};
    {
        const int colw = w * 64;
#pragma unroll
        for (int ks = 0; ks < 512; ks += 32) {
            bf16x8 af[4];
#pragma unroll
            for (int rf = 0; rf < 4; ++rf) {
                int row = rf * 16 + lo;
                int byte = (row * 1024 + (ks + 8 * hi) * 2) ^ ((row & 7) << 4);
                af[rf] = *(const bf16x8*)(smA + byte);
            }
#pragma unroll
            for (int cf = 0; cf < 4; ++cf) {
                bf16x8 bfr = *(const bf16x8*)(u1t + (size_t)(colw + cf * 16 + lo) * 512 + ks + 8 * hi);
#pragma unroll
                for (int rf = 0; rf < 4; ++rf)
                    aC[rf][cf] = __builtin_amdgcn_mfma_f32_16x16x32_bf16(af[rf], bfr, aC[rf][cf], 0, 0, 0);
            }
        }
    }
    __syncthreads();  // X reads done

    // ---- 5. write hid2 -> smA ----
    {
        const int colw = w * 64;
#pragma unroll
        for (int cf = 0; cf < 4; ++cf) {
            int col = colw + cf * 16 + lo;
            float bb = ub1[col];
#pragma unroll
            for (int rf = 0; rf < 4; ++rf) {
#pragma unroll
                for (int r = 0; r < 4; ++r) {
                    float v = fmaxf(aC[rf][cf][r] + bb, 0.f);
                    int row = rf * 16 + hi * 4 + r;
                    int byte = (row * 1024 + col * 2) ^ ((row & 7) << 4);
                    *(unsigned short*)(smA + byte) = f2bf(v);
                }
            }
        }
    }
    __syncthreads();

    // ---- 6. phase D: out = h + hid2 @ U2 + ub2; wave w cols [32w, 32w+32) ----
    {
        const int colw = w * 32;
        f32x4 aD[4][2];
#pragma unroll
        for (int i = 0; i < 4; ++i)
#pragma unroll
            for (int j = 0; j < 2; ++j) aD[i][j] = (f32x4){0.f, 0.f, 0.f, 0.f};

#pragma unroll
        for (int ks = 0; ks < 512; ks += 32) {
            bf16x8 af[4];
#pragma unroll
            for (int rf = 0; rf < 4; ++rf) {
                int row = rf * 16 + lo;
                int byte = (row * 1024 + (ks + 8 * hi) * 2) ^ ((row & 7) << 4);
                af[rf] = *(const bf16x8*)(smA + byte);
            }
#pragma unroll
            for (int cf = 0; cf < 2; ++cf) {
                bf16x8 bfr = *(const bf16x8*)(u2t + (size_t)(colw + cf * 16 + lo) * 512 + ks + 8 * hi);
#pragma unroll
                for (int rf = 0; rf < 4; ++rf)
                    aD[rf][cf] = __builtin_amdgcn_mfma_f32_16x16x32_bf16(af[rf], bfr, aD[rf][cf], 0, 0, 0);
            }
        }

#pragma unroll
        for (int cf = 0; cf < 2; ++cf) {
            int col = colw + cf * 16 + lo;
            float bb = ub2[col];
#pragma unroll
            for (int rf = 0; rf < 4; ++rf) {
#pragma unroll
                for (int r = 0; r < 4; ++r) {
                    int row = rf * 16 + hi * 4 + r;
                    int grow = d0 + row;
                    if (grow < nrows) {
                        size_t o = (size_t)grow * H_ + col;
                        float hv = hb[o];
                        __builtin_nontemporal_store(hv + aD[rf][cf][r] + bb, &outb[o]);
                    }
                }
            }
        }
    }
}

extern "C" void kernel_launch(void* const* d_in, const int* in_sizes, int n_in,
                              void* d_out, int out_size, void* d_ws, size_t ws_size,
                              hipStream_t stream) {
    const float* h      = (const float*)d_in[0];
    const int*   eidx   = (const int*)d_in[1];
    const float* msg_w1 = (const float*)d_in[2];
    const float* msg_b1 = (const float*)d_in[3];
    const float* msg_w2 = (const float*)d_in[4];
    const float* msg_b2 = (const float*)d_in[5];
    const float* upd_w1 = (const float*)d_in[6];
    const float* upd_b1 = (const float*)d_in[7];
    const float* upd_w2 = (const float*)d_in[8];
    const float* upd_b2 = (const float*)d_in[9];
    float* out = (float*)d_out;

    // ---- workspace layout: try batch-merged, fall back to per-batch ----
    const size_t smallSizes[] = {
        (size_t)2 * N_ * 1024 * 2,   // PQ      (merged: [2N][1024])
        (size_t)2 * N_ * 512 * 2,    // hsum    (merged: [2N][512])
        1024 * 256 * 2,              // w1pq
        256 * 512 * 2,               // w2t
        512 * 512 * 2,               // u1t
        256 * 512 * 2,               // u2t
        (size_t)N_ * 4,              // cnt
        (size_t)(N_ + 1) * 4,        // offs
        (size_t)N_ * 4,              // cursor
        (size_t)E_ * 4               // srcs
    };
    size_t needMerged = 0;
    for (int i = 0; i < 10; ++i) needMerged += (smallSizes[i] + 255) & ~(size_t)255;
    const bool merged = (ws_size >= needMerged);

    char* ws = (char*)d_ws;
    size_t off = 0;
    auto alloc = [&](size_t bytes) {
        char* p = ws + off;
        off = (off + bytes + 255) & ~(size_t)255;
        return p;
    };
    const int PQ_ROWS = merged ? 2 * N_ : N_;
    unsigned short* PQ   = (unsigned short*)alloc((size_t)PQ_ROWS * 1024 * 2);
    unsigned short* hsum = (unsigned short*)alloc((size_t)PQ_ROWS * 512 * 2);
    unsigned short* w1pq = (unsigned short*)alloc(1024 * 256 * 2);
    unsigned short* w2t  = (unsigned short*)alloc(256 * 512 * 2);
    unsigned short* u1t  = (unsigned short*)alloc(512 * 512 * 2);
    unsigned short* u2t  = (unsigned short*)alloc(256 * 512 * 2);
    int* cnt    = (int*)alloc(N_ * 4);
    int* offs   = (int*)alloc((N_ + 1) * 4);
    int* cursor = (int*)alloc(N_ * 4);
    int* srcs   = (int*)alloc(E_ * 4);
    if (ws_size < off) return;

    hipMemsetAsync(cnt, 0, N_ * 4, stream);
    conv_all<<<384, 256, 0, stream>>>(msg_w1, msg_w2, upd_w1, upd_w2, w1pq, w2t, u1t, u2t);

    hist_kernel<<<256, 256, 0, stream>>>(eidx, cnt);
    scan_kernel<<<1, 1024, 0, stream>>>(cnt, offs, cursor);
    scatter_kernel<<<256, 256, 0, stream>>>(eidx, cursor, srcs);

    if (merged) {
        const int nrows = 2 * N_;                    // 40000
        const int nblk64 = (nrows + 63) / 64;        // 625
        pq_gemm<<<nblk64 * 2, 512, 0, stream>>>(h, w1pq, PQ, nrows);
        gather_kernel<<<2048, 256, 0, stream>>>(PQ, srcs, offs, msg_b1, hsum, nrows);
        // mlp per-batch: two 313-block launches (each one resident round)
        const int nblkB = (N_ + 63) / 64;            // 313
        for (int b = 0; b < B_; ++b) {
            size_t ro = (size_t)b * N_;
            mlp_kernel<<<nblkB, 512, 0, stream>>>(hsum + ro * 512, cnt, w2t, msg_b2,
                                                  u1t, upd_b1, u2t, upd_b2,
                                                  h + ro * H_, out + ro * H_, N_);
        }
    } else {
        const int nblk64 = (N_ + 63) / 64;           // 313
        for (int b = 0; b < B_; ++b) {
            const float* hb = h + (size_t)b * N_ * H_;
            pq_gemm<<<nblk64 * 2, 512, 0, stream>>>(hb, w1pq, PQ, N_);
            gather_kernel<<<2048, 256, 0, stream>>>(PQ, srcs, offs, msg_b1, hsum, N_);
            mlp_kernel<<<nblk64, 512, 0, stream>>>(hsum, cnt, w2t, msg_b2,
                                                   u1t, upd_b1, u2t, upd_b2,
                                                   hb, out + (size_t)b * N_ * H_, N_);
        }
    }
}